// Round 4
// baseline (744.815 us; speedup 1.0000x reference)
//
#include <hip/hip_runtime.h>
#include <hip/hip_bf16.h>
#include <stdint.h>

#define NS   200000
#define ND   100000
#define NTOT 300000
#define NE   1600000
#define DINK 128
#define NH   8
#define DH   16
#define HD   128
#define NAUG 144
#define NEG  0.2f

typedef __attribute__((ext_vector_type(8))) short short8;
typedef __attribute__((ext_vector_type(4))) float f32x4;

__device__ inline uint32_t bf16rne(uint32_t u) {
  return (u + 0x7fffu + ((u >> 16) & 1u)) >> 16;
}
__device__ inline uint32_t pack_bf2(float a, float b) {
  union { float f; uint32_t u; } ua, ub; ua.f = a; ub.f = b;
  return (bf16rne(ua.u) & 0xffffu) | (bf16rne(ub.u) << 16);
}

// Build augmented weight [128][144] = [W | W@attn_l | W@attn_r]
__global__ void k_build_waug(const float* __restrict__ W, const float* __restrict__ al,
                             const float* __restrict__ ar, float* __restrict__ Waug) {
  int idx = blockIdx.x * blockDim.x + threadIdx.x;
  if (idx >= DINK * NAUG) return;
  int k = idx / NAUG, c = idx % NAUG;
  float v;
  if (c < HD) {
    v = W[k * HD + c];
  } else {
    int hh = (c - HD) & 7;
    const float* a = (c < HD + NH) ? al : ar;
    float s = 0.f;
    for (int d = 0; d < DH; ++d) s += W[k * HD + hh * DH + d] * a[hh * DH + d];
    v = s;
  }
  Waug[k * NAUG + c] = v;
}

// MFMA bf16 GEMM: [300k x 128] @ [128 x 144] -> h (bf16) + el/er (f32)
// 4 waves/block, 64 rows/block, full K in LDS, XOR-swizzled slots.
__global__ __launch_bounds__(256) void k_gemm_mfma(
    const float* __restrict__ fs, const float* __restrict__ fd,
    const float* __restrict__ Waug, __hip_bfloat16* __restrict__ hbf,
    float* __restrict__ el, float* __restrict__ er) {
  __shared__ short lds_w[NAUG * DINK];   // W^T as [n][k] bf16, 16B slots XOR'd by (n&7)<<4
  __shared__ short lds_a[64 * DINK];     // A as [m][k] bf16, 16B slots XOR'd by (m&7)<<4
  int tid = threadIdx.x;
  int m0 = blockIdx.x * 64;

  for (int idx = tid; idx < NAUG * DINK; idx += 256) {
    int k = idx / NAUG, n = idx - k * NAUG;       // Waug[k][n]
    union { float f; uint32_t u; } uv; uv.f = Waug[idx];
    uint32_t off = ((uint32_t)(n * DINK + k) * 2u) ^ ((uint32_t)(n & 7) << 4);
    *(short*)((char*)lds_w + off) = (short)bf16rne(uv.u);
  }
  {
    int row = tid >> 2;
    int grow = m0 + row;
    int cbase = (tid & 3) * 32;
    bool valid = grow < NTOT;
    const float* base = valid ? ((grow < NS) ? (fs + (size_t)grow * DINK)
                                             : (fd + (size_t)(grow - NS) * DINK)) : (const float*)0;
#pragma unroll
    for (int c = 0; c < 4; ++c) {
      float4 v0 = valid ? *(const float4*)(base + cbase + c * 8)     : make_float4(0,0,0,0);
      float4 v1 = valid ? *(const float4*)(base + cbase + c * 8 + 4) : make_float4(0,0,0,0);
      uint4 p;
      p.x = pack_bf2(v0.x, v0.y); p.y = pack_bf2(v0.z, v0.w);
      p.z = pack_bf2(v1.x, v1.y); p.w = pack_bf2(v1.z, v1.w);
      uint32_t off = ((uint32_t)(row * DINK + cbase + c * 8) * 2u) ^ ((uint32_t)(row & 7) << 4);
      *(uint4*)((char*)lds_a + off) = p;
    }
  }
  __syncthreads();

  int wid = tid >> 6, lane = tid & 63;
  int lr = lane & 15, lg = lane >> 4;
  short8 af[4];
#pragma unroll
  for (int s = 0; s < 4; ++s) {
    uint32_t off = ((uint32_t)((wid * 16 + lr) * DINK + s * 32 + lg * 8) * 2u)
                 ^ ((uint32_t)(lr & 7) << 4);
    af[s] = *(short8*)((char*)lds_a + off);
  }
  int orow0 = m0 + wid * 16 + lg * 4;
#pragma unroll
  for (int t = 0; t < 9; ++t) {
    f32x4 acc = {0.f, 0.f, 0.f, 0.f};
#pragma unroll
    for (int s = 0; s < 4; ++s) {
      uint32_t off = ((uint32_t)((t * 16 + lr) * DINK + s * 32 + lg * 8) * 2u)
                   ^ ((uint32_t)(lr & 7) << 4);
      short8 bfr = *(short8*)((char*)lds_w + off);
      acc = __builtin_amdgcn_mfma_f32_16x16x32_bf16(af[s], bfr, acc, 0, 0, 0);
    }
#pragma unroll
    for (int j = 0; j < 4; ++j) {
      int row = orow0 + j;
      if (row >= NTOT) continue;
      float v = acc[j];
      if (t < 8)          hbf[(size_t)row * HD + t * 16 + lr] = __float2bfloat16(v);
      else if (lr < 8)    el[(size_t)row * NH + lr] = v;
      else                er[(size_t)row * NH + (lr - 8)] = v;
    }
  }
}

__global__ void k_hist(const int* __restrict__ idxs, int* __restrict__ cnt) {
  int e = blockIdx.x * 256 + threadIdx.x;
  if (e < NE) atomicAdd(&cnt[idxs[e]], 1);
}

__global__ void k_scan1(const int* __restrict__ deg, int* __restrict__ bsum, int n) {
  __shared__ int sd[1024];
  int i = blockIdx.x * 1024 + threadIdx.x;
  sd[threadIdx.x] = (i < n) ? deg[i] : 0;
  __syncthreads();
  for (int s = 512; s > 0; s >>= 1) {
    if (threadIdx.x < s) sd[threadIdx.x] += sd[threadIdx.x + s];
    __syncthreads();
  }
  if (threadIdx.x == 0) bsum[blockIdx.x] = sd[0];
}

__global__ void k_scan2(int* __restrict__ bsum, int nb) {
  if (threadIdx.x == 0 && blockIdx.x == 0) {
    int run = 0;
    for (int b = 0; b < nb; ++b) { int t = bsum[b]; bsum[b] = run; run += t; }
  }
}

__global__ void k_scan3(const int* __restrict__ deg, const int* __restrict__ bsum,
                        int* __restrict__ offs, int* __restrict__ cur, int n) {
  __shared__ int sd[1024];
  int i = blockIdx.x * 1024 + threadIdx.x;
  int v = (i < n) ? deg[i] : 0;
  sd[threadIdx.x] = v;
  __syncthreads();
  for (int s = 1; s < 1024; s <<= 1) {
    int t = (threadIdx.x >= (unsigned)s) ? sd[threadIdx.x - s] : 0;
    __syncthreads();
    sd[threadIdx.x] += t;
    __syncthreads();
  }
  if (i < n) {
    int e = bsum[blockIdx.x] + sd[threadIdx.x] - v;   // exclusive prefix
    offs[i] = e;
    cur[i] = e;
  }
}

// counting-sort edges by src (bins exact, so output is src-sorted)
__global__ void k_scatter_src(const int* __restrict__ esrc, const int* __restrict__ edst,
                              int* __restrict__ cur, int* __restrict__ esS, int* __restrict__ edS) {
  int e = blockIdx.x * 256 + threadIdx.x;
  if (e < NE) {
    int s = esrc[e];
    int p = atomicAdd(&cur[s], 1);
    esS[p] = s;
    edS[p] = edst[e];
  }
}

// CSR by dst consuming src-sorted edges -> per-row src lists are ~ascending
__global__ void k_scatter_dst(const int* __restrict__ esS, const int* __restrict__ edS,
                              int* __restrict__ cur, int* __restrict__ csr) {
  int e = blockIdx.x * 256 + threadIdx.x;
  if (e < NE) {
    int d = edS[e];
    int p = atomicAdd(&cur[d], 1);
    csr[p] = esS[e];
  }
}

// One wave per dst node, edge loop unrolled x4.
__global__ __launch_bounds__(256) void k_agg(const int* __restrict__ csr, const int* __restrict__ offs,
    const int* __restrict__ deg, const float* __restrict__ el, const float* __restrict__ er,
    const uint32_t* __restrict__ h2, const float* __restrict__ bias, float* __restrict__ out) {
  int wid = (int)((blockIdx.x * blockDim.x + threadIdx.x) >> 6);
  int lane = threadIdx.x & 63;
  if (wid >= ND) return;
  int g = NS + wid;
  int hh = lane >> 3;
  float erv = er[(size_t)g * NH + hh];
  float w0 = el[(size_t)g * NH + hh] + erv;
  w0 = (w0 < 0.f) ? NEG * w0 : w0;
  w0 = __expf(w0);
  uint32_t hv = h2[(size_t)g * 64 + lane];
  float acc0 = w0 * __uint_as_float(hv << 16);
  float acc1 = w0 * __uint_as_float(hv & 0xffff0000u);
  float z = w0;
  int off = offs[wid], n = deg[wid];
  int t = 0;
  for (; t + 4 <= n; t += 4) {
    int s0 = csr[off + t], s1 = csr[off + t + 1], s2 = csr[off + t + 2], s3 = csr[off + t + 3];
    float e0 = el[(size_t)s0 * NH + hh];
    float e1 = el[(size_t)s1 * NH + hh];
    float e2 = el[(size_t)s2 * NH + hh];
    float e3 = el[(size_t)s3 * NH + hh];
    uint32_t b0 = h2[(size_t)s0 * 64 + lane];
    uint32_t b1 = h2[(size_t)s1 * 64 + lane];
    uint32_t b2 = h2[(size_t)s2 * 64 + lane];
    uint32_t b3 = h2[(size_t)s3 * 64 + lane];
    float w;
    w = e0 + erv; w = (w < 0.f) ? NEG * w : w; w = __expf(w);
    acc0 = fmaf(w, __uint_as_float(b0 << 16), acc0);
    acc1 = fmaf(w, __uint_as_float(b0 & 0xffff0000u), acc1); z += w;
    w = e1 + erv; w = (w < 0.f) ? NEG * w : w; w = __expf(w);
    acc0 = fmaf(w, __uint_as_float(b1 << 16), acc0);
    acc1 = fmaf(w, __uint_as_float(b1 & 0xffff0000u), acc1); z += w;
    w = e2 + erv; w = (w < 0.f) ? NEG * w : w; w = __expf(w);
    acc0 = fmaf(w, __uint_as_float(b2 << 16), acc0);
    acc1 = fmaf(w, __uint_as_float(b2 & 0xffff0000u), acc1); z += w;
    w = e3 + erv; w = (w < 0.f) ? NEG * w : w; w = __expf(w);
    acc0 = fmaf(w, __uint_as_float(b3 << 16), acc0);
    acc1 = fmaf(w, __uint_as_float(b3 & 0xffff0000u), acc1); z += w;
  }
  for (; t < n; ++t) {
    int src = csr[off + t];
    float wv = el[(size_t)src * NH + hh] + erv;
    wv = (wv < 0.f) ? NEG * wv : wv;
    wv = __expf(wv);
    uint32_t hb = h2[(size_t)src * 64 + lane];
    acc0 = fmaf(wv, __uint_as_float(hb << 16), acc0);
    acc1 = fmaf(wv, __uint_as_float(hb & 0xffff0000u), acc1);
    z += wv;
  }
  float inv = 1.f / z;
  int c = lane << 1;
  float2 o = make_float2(acc0 * inv + bias[c], acc1 * inv + bias[c + 1]);
  *(float2*)&out[(size_t)wid * HD + c] = o;
}

extern "C" void kernel_launch(void* const* d_in, const int* in_sizes, int n_in,
                              void* d_out, int out_size, void* d_ws, size_t ws_size,
                              hipStream_t stream) {
  const float* fs   = (const float*)d_in[0];
  const float* fd   = (const float*)d_in[1];
  const float* W    = (const float*)d_in[2];
  const float* al   = (const float*)d_in[3];
  const float* ar   = (const float*)d_in[4];
  const float* bias = (const float*)d_in[5];
  const int* esrc   = (const int*)d_in[6];
  const int* edst   = (const int*)d_in[7];
  float* out = (float*)d_out;
  (void)in_sizes; (void)n_in; (void)out_size; (void)ws_size;

  char* ws = (char*)d_ws;
  size_t o = 0;
  auto alloc = [&](size_t b) { size_t r = o; o += (b + 255) & ~(size_t)255; return r; };
  float*  Waug  = (float*)(ws + alloc((size_t)DINK * NAUG * 4));
  __hip_bfloat16* hbf = (__hip_bfloat16*)(ws + alloc((size_t)NTOT * HD * 2));
  float*  el    = (float*)(ws + alloc((size_t)NTOT * NH * 4));
  float*  er    = (float*)(ws + alloc((size_t)NTOT * NH * 4));
  int*    deg   = (int*)(ws + alloc((size_t)ND * 4));
  int*    offs  = (int*)(ws + alloc((size_t)ND * 4));
  int*    cur   = (int*)(ws + alloc((size_t)ND * 4));
  int*    sdeg  = (int*)(ws + alloc((size_t)NS * 4));
  int*    scur  = (int*)(ws + alloc((size_t)NS * 4));
  int*    bsum  = (int*)(ws + alloc(1024));
  int*    csr   = (int*)(ws + alloc((size_t)NE * 4));
  int*    esS   = (int*)(ws + alloc((size_t)NE * 4));
  int*    edS   = (int*)(ws + alloc((size_t)NE * 4));

  hipMemsetAsync(deg, 0, (size_t)ND * 4, stream);
  hipMemsetAsync(sdeg, 0, (size_t)NS * 4, stream);
  k_build_waug<<<(DINK * NAUG + 255) / 256, 256, 0, stream>>>(W, al, ar, Waug);
  k_hist<<<NE / 256, 256, 0, stream>>>(edst, deg);
  k_hist<<<NE / 256, 256, 0, stream>>>(esrc, sdeg);
  k_gemm_mfma<<<(NTOT + 63) / 64, 256, 0, stream>>>(fs, fd, Waug, hbf, el, er);

  int nbS = (NS + 1023) / 1024;
  k_scan1<<<nbS, 1024, 0, stream>>>(sdeg, bsum, NS);
  k_scan2<<<1, 64, 0, stream>>>(bsum, nbS);
  k_scan3<<<nbS, 1024, 0, stream>>>(sdeg, bsum, scur, scur, NS);
  k_scatter_src<<<NE / 256, 256, 0, stream>>>(esrc, edst, scur, esS, edS);

  int nbD = (ND + 1023) / 1024;
  k_scan1<<<nbD, 1024, 0, stream>>>(deg, bsum, ND);
  k_scan2<<<1, 64, 0, stream>>>(bsum, nbD);
  k_scan3<<<nbD, 1024, 0, stream>>>(deg, bsum, offs, cur, ND);
  k_scatter_dst<<<NE / 256, 256, 0, stream>>>(esS, edS, cur, csr);

  k_agg<<<ND / 4, 256, 0, stream>>>(csr, offs, deg, el, er, (const uint32_t*)hbf, bias, out);
}

// Round 5
// 604.447 us; speedup vs baseline: 1.2322x; 1.2322x over previous
//
#include <hip/hip_runtime.h>
#include <hip/hip_bf16.h>
#include <stdint.h>

#define NS   200000
#define ND   100000
#define NTOT 300000
#define NE   1600000
#define DINK 128
#define NH   8
#define DH   16
#define HD   128
#define NAUG 144
#define NEG  0.2f

#define NBUK  1024
#define BSHIFT 8          // src >> 8 -> bucket (200000>>8 = 781 bins used)
#define EPB   8192        // edges per partition block
#define NPB   196         // ceil(NE / EPB)

typedef __attribute__((ext_vector_type(8))) short short8;
typedef __attribute__((ext_vector_type(4))) float f32x4;

__device__ inline uint32_t bf16rne(uint32_t u) {
  return (u + 0x7fffu + ((u >> 16) & 1u)) >> 16;
}
__device__ inline uint32_t pack_bf2(float a, float b) {
  union { float f; uint32_t u; } ua, ub; ua.f = a; ub.f = b;
  return (bf16rne(ua.u) & 0xffffu) | (bf16rne(ub.u) << 16);
}

// Build augmented weight [128][144] = [W | W@attn_l | W@attn_r]
__global__ void k_build_waug(const float* __restrict__ W, const float* __restrict__ al,
                             const float* __restrict__ ar, float* __restrict__ Waug) {
  int idx = blockIdx.x * blockDim.x + threadIdx.x;
  if (idx >= DINK * NAUG) return;
  int k = idx / NAUG, c = idx % NAUG;
  float v;
  if (c < HD) {
    v = W[k * HD + c];
  } else {
    int hh = (c - HD) & 7;
    const float* a = (c < HD + NH) ? al : ar;
    float s = 0.f;
    for (int d = 0; d < DH; ++d) s += W[k * HD + hh * DH + d] * a[hh * DH + d];
    v = s;
  }
  Waug[k * NAUG + c] = v;
}

// MFMA bf16 GEMM: [300k x 128] @ [128 x 144] -> h (bf16) + el/er (f32)
__global__ __launch_bounds__(256) void k_gemm_mfma(
    const float* __restrict__ fs, const float* __restrict__ fd,
    const float* __restrict__ Waug, __hip_bfloat16* __restrict__ hbf,
    float* __restrict__ el, float* __restrict__ er) {
  __shared__ short lds_w[NAUG * DINK];   // W^T [n][k] bf16, 16B slots XOR'd by (n&7)<<4
  __shared__ short lds_a[64 * DINK];     // A   [m][k] bf16, 16B slots XOR'd by (m&7)<<4
  int tid = threadIdx.x;
  int m0 = blockIdx.x * 64;

  for (int idx = tid; idx < NAUG * DINK; idx += 256) {
    int k = idx / NAUG, n = idx - k * NAUG;
    union { float f; uint32_t u; } uv; uv.f = Waug[idx];
    uint32_t off = ((uint32_t)(n * DINK + k) * 2u) ^ ((uint32_t)(n & 7) << 4);
    *(short*)((char*)lds_w + off) = (short)bf16rne(uv.u);
  }
  {
    int row = tid >> 2;
    int grow = m0 + row;
    int cbase = (tid & 3) * 32;
    bool valid = grow < NTOT;
    const float* base = valid ? ((grow < NS) ? (fs + (size_t)grow * DINK)
                                             : (fd + (size_t)(grow - NS) * DINK)) : (const float*)0;
#pragma unroll
    for (int c = 0; c < 4; ++c) {
      float4 v0 = valid ? *(const float4*)(base + cbase + c * 8)     : make_float4(0,0,0,0);
      float4 v1 = valid ? *(const float4*)(base + cbase + c * 8 + 4) : make_float4(0,0,0,0);
      uint4 p;
      p.x = pack_bf2(v0.x, v0.y); p.y = pack_bf2(v0.z, v0.w);
      p.z = pack_bf2(v1.x, v1.y); p.w = pack_bf2(v1.z, v1.w);
      uint32_t off = ((uint32_t)(row * DINK + cbase + c * 8) * 2u) ^ ((uint32_t)(row & 7) << 4);
      *(uint4*)((char*)lds_a + off) = p;
    }
  }
  __syncthreads();

  int wid = tid >> 6, lane = tid & 63;
  int lr = lane & 15, lg = lane >> 4;
  short8 af[4];
#pragma unroll
  for (int s = 0; s < 4; ++s) {
    uint32_t off = ((uint32_t)((wid * 16 + lr) * DINK + s * 32 + lg * 8) * 2u)
                 ^ ((uint32_t)(lr & 7) << 4);
    af[s] = *(short8*)((char*)lds_a + off);
  }
  int orow0 = m0 + wid * 16 + lg * 4;
#pragma unroll
  for (int t = 0; t < 9; ++t) {
    f32x4 acc = {0.f, 0.f, 0.f, 0.f};
#pragma unroll
    for (int s = 0; s < 4; ++s) {
      uint32_t off = ((uint32_t)((t * 16 + lr) * DINK + s * 32 + lg * 8) * 2u)
                   ^ ((uint32_t)(lr & 7) << 4);
      short8 bfr = *(short8*)((char*)lds_w + off);
      acc = __builtin_amdgcn_mfma_f32_16x16x32_bf16(af[s], bfr, acc, 0, 0, 0);
    }
#pragma unroll
    for (int j = 0; j < 4; ++j) {
      int row = orow0 + j;
      if (row >= NTOT) continue;
      float v = acc[j];
      if (t < 8)          hbf[(size_t)row * HD + t * 16 + lr] = __float2bfloat16(v);
      else if (lr < 8)    el[(size_t)row * NH + lr] = v;
      else                er[(size_t)row * NH + (lr - 8)] = v;
    }
  }
}

// One pass over edges: dst-degree (global atomics) + src-bucket histogram (LDS then merge)
__global__ __launch_bounds__(256) void k_hist_fused(
    const int* __restrict__ esrc, const int* __restrict__ edst,
    int* __restrict__ deg, int* __restrict__ bhist) {
  __shared__ int lcnt[NBUK];
  int tid = threadIdx.x;
  for (int b = tid; b < NBUK; b += 256) lcnt[b] = 0;
  __syncthreads();
  for (int e = blockIdx.x * 256 + tid; e < NE; e += gridDim.x * 256) {
    int s = esrc[e];
    int d = edst[e];
    atomicAdd(&lcnt[s >> BSHIFT], 1);
    atomicAdd(&deg[d], 1);
  }
  __syncthreads();
  for (int b = tid; b < NBUK; b += 256) {
    int c = lcnt[b];
    if (c) atomicAdd(&bhist[b], c);
  }
}

// Scan 1024 bucket counts -> boffs (exclusive) and bcur
__global__ void k_scan_buckets(const int* __restrict__ bhist, int* __restrict__ bcur) {
  __shared__ int sd[NBUK];
  int t = threadIdx.x;
  int v = bhist[t];
  sd[t] = v;
  __syncthreads();
  for (int s = 1; s < NBUK; s <<= 1) {
    int a = (t >= s) ? sd[t - s] : 0;
    __syncthreads();
    sd[t] += a;
    __syncthreads();
  }
  bcur[t] = sd[t] - v;   // exclusive prefix
}

// LDS-binned partition of edges by src-bucket; output int2(src,dst) bucket-major
__global__ __launch_bounds__(256) void k_partition(
    const int* __restrict__ esrc, const int* __restrict__ edst,
    int* __restrict__ bcur, int2* __restrict__ part) {
  __shared__ int lcnt[NBUK];
  __shared__ int lbase[NBUK];
  int tid = threadIdx.x;
  int e0 = blockIdx.x * EPB;
  for (int b = tid; b < NBUK; b += 256) lcnt[b] = 0;
  __syncthreads();
#pragma unroll
  for (int i = 0; i < EPB / 256; ++i) {
    int e = e0 + i * 256 + tid;
    if (e < NE) atomicAdd(&lcnt[esrc[e] >> BSHIFT], 1);
  }
  __syncthreads();
  for (int b = tid; b < NBUK; b += 256) {
    int c = lcnt[b];
    lbase[b] = c ? atomicAdd(&bcur[b], c) : 0;
  }
  __syncthreads();
#pragma unroll
  for (int i = 0; i < EPB / 256; ++i) {
    int e = e0 + i * 256 + tid;
    if (e < NE) {
      int s = esrc[e];
      int d = edst[e];
      int slot = atomicAdd(&lbase[s >> BSHIFT], 1);
      part[slot] = make_int2(s, d);
    }
  }
}

__global__ void k_scan1(const int* __restrict__ deg, int* __restrict__ bsum, int n) {
  __shared__ int sd[1024];
  int i = blockIdx.x * 1024 + threadIdx.x;
  sd[threadIdx.x] = (i < n) ? deg[i] : 0;
  __syncthreads();
  for (int s = 512; s > 0; s >>= 1) {
    if (threadIdx.x < s) sd[threadIdx.x] += sd[threadIdx.x + s];
    __syncthreads();
  }
  if (threadIdx.x == 0) bsum[blockIdx.x] = sd[0];
}

__global__ void k_scan2(int* __restrict__ bsum, int nb) {
  if (threadIdx.x == 0 && blockIdx.x == 0) {
    int run = 0;
    for (int b = 0; b < nb; ++b) { int t = bsum[b]; bsum[b] = run; run += t; }
  }
}

__global__ void k_scan3(const int* __restrict__ deg, const int* __restrict__ bsum,
                        int* __restrict__ offs, int* __restrict__ cur, int n) {
  __shared__ int sd[1024];
  int i = blockIdx.x * 1024 + threadIdx.x;
  int v = (i < n) ? deg[i] : 0;
  sd[threadIdx.x] = v;
  __syncthreads();
  for (int s = 1; s < 1024; s <<= 1) {
    int t = (threadIdx.x >= (unsigned)s) ? sd[threadIdx.x - s] : 0;
    __syncthreads();
    sd[threadIdx.x] += t;
    __syncthreads();
  }
  if (i < n) {
    int e = bsum[blockIdx.x] + sd[threadIdx.x] - v;
    offs[i] = e;
    cur[i] = e;
  }
}

// CSR by dst consuming bucket-major edges -> rows are ~src-bucket-ascending
__global__ void k_scatter_dst(const int2* __restrict__ part,
                              int* __restrict__ cur, int* __restrict__ csr) {
  int e = blockIdx.x * 256 + threadIdx.x;
  if (e < NE) {
    int2 sd = part[e];
    int p = atomicAdd(&cur[sd.y], 1);
    csr[p] = sd.x;
  }
}

// One wave per dst node, edge loop unrolled x4.
__global__ __launch_bounds__(256) void k_agg(const int* __restrict__ csr, const int* __restrict__ offs,
    const int* __restrict__ deg, const float* __restrict__ el, const float* __restrict__ er,
    const uint32_t* __restrict__ h2, const float* __restrict__ bias, float* __restrict__ out) {
  int wid = (int)((blockIdx.x * blockDim.x + threadIdx.x) >> 6);
  int lane = threadIdx.x & 63;
  if (wid >= ND) return;
  int g = NS + wid;
  int hh = lane >> 3;
  float erv = er[(size_t)g * NH + hh];
  float w0 = el[(size_t)g * NH + hh] + erv;
  w0 = (w0 < 0.f) ? NEG * w0 : w0;
  w0 = __expf(w0);
  uint32_t hv = h2[(size_t)g * 64 + lane];
  float acc0 = w0 * __uint_as_float(hv << 16);
  float acc1 = w0 * __uint_as_float(hv & 0xffff0000u);
  float z = w0;
  int off = offs[wid], n = deg[wid];
  int t = 0;
  for (; t + 4 <= n; t += 4) {
    int s0 = csr[off + t], s1 = csr[off + t + 1], s2 = csr[off + t + 2], s3 = csr[off + t + 3];
    float e0 = el[(size_t)s0 * NH + hh];
    float e1 = el[(size_t)s1 * NH + hh];
    float e2 = el[(size_t)s2 * NH + hh];
    float e3 = el[(size_t)s3 * NH + hh];
    uint32_t b0 = h2[(size_t)s0 * 64 + lane];
    uint32_t b1 = h2[(size_t)s1 * 64 + lane];
    uint32_t b2 = h2[(size_t)s2 * 64 + lane];
    uint32_t b3 = h2[(size_t)s3 * 64 + lane];
    float w;
    w = e0 + erv; w = (w < 0.f) ? NEG * w : w; w = __expf(w);
    acc0 = fmaf(w, __uint_as_float(b0 << 16), acc0);
    acc1 = fmaf(w, __uint_as_float(b0 & 0xffff0000u), acc1); z += w;
    w = e1 + erv; w = (w < 0.f) ? NEG * w : w; w = __expf(w);
    acc0 = fmaf(w, __uint_as_float(b1 << 16), acc0);
    acc1 = fmaf(w, __uint_as_float(b1 & 0xffff0000u), acc1); z += w;
    w = e2 + erv; w = (w < 0.f) ? NEG * w : w; w = __expf(w);
    acc0 = fmaf(w, __uint_as_float(b2 << 16), acc0);
    acc1 = fmaf(w, __uint_as_float(b2 & 0xffff0000u), acc1); z += w;
    w = e3 + erv; w = (w < 0.f) ? NEG * w : w; w = __expf(w);
    acc0 = fmaf(w, __uint_as_float(b3 << 16), acc0);
    acc1 = fmaf(w, __uint_as_float(b3 & 0xffff0000u), acc1); z += w;
  }
  for (; t < n; ++t) {
    int src = csr[off + t];
    float wv = el[(size_t)src * NH + hh] + erv;
    wv = (wv < 0.f) ? NEG * wv : wv;
    wv = __expf(wv);
    uint32_t hb = h2[(size_t)src * 64 + lane];
    acc0 = fmaf(wv, __uint_as_float(hb << 16), acc0);
    acc1 = fmaf(wv, __uint_as_float(hb & 0xffff0000u), acc1);
    z += wv;
  }
  float inv = 1.f / z;
  int c = lane << 1;
  float2 o = make_float2(acc0 * inv + bias[c], acc1 * inv + bias[c + 1]);
  *(float2*)&out[(size_t)wid * HD + c] = o;
}

extern "C" void kernel_launch(void* const* d_in, const int* in_sizes, int n_in,
                              void* d_out, int out_size, void* d_ws, size_t ws_size,
                              hipStream_t stream) {
  const float* fs   = (const float*)d_in[0];
  const float* fd   = (const float*)d_in[1];
  const float* W    = (const float*)d_in[2];
  const float* al   = (const float*)d_in[3];
  const float* ar   = (const float*)d_in[4];
  const float* bias = (const float*)d_in[5];
  const int* esrc   = (const int*)d_in[6];
  const int* edst   = (const int*)d_in[7];
  float* out = (float*)d_out;
  (void)in_sizes; (void)n_in; (void)out_size; (void)ws_size;

  char* ws = (char*)d_ws;
  size_t o = 0;
  auto alloc = [&](size_t b) { size_t r = o; o += (b + 255) & ~(size_t)255; return r; };
  float*  Waug  = (float*)(ws + alloc((size_t)DINK * NAUG * 4));
  __hip_bfloat16* hbf = (__hip_bfloat16*)(ws + alloc((size_t)NTOT * HD * 2));
  float*  el    = (float*)(ws + alloc((size_t)NTOT * NH * 4));
  float*  er    = (float*)(ws + alloc((size_t)NTOT * NH * 4));
  int*    deg   = (int*)(ws + alloc((size_t)ND * 4));
  int*    offs  = (int*)(ws + alloc((size_t)ND * 4));
  int*    cur   = (int*)(ws + alloc((size_t)ND * 4));
  int*    bhist = (int*)(ws + alloc((size_t)NBUK * 4));
  int*    bcur  = (int*)(ws + alloc((size_t)NBUK * 4));
  int*    bsum  = (int*)(ws + alloc(1024));
  int*    csr   = (int*)(ws + alloc((size_t)NE * 4));
  int2*   part  = (int2*)(ws + alloc((size_t)NE * 8));

  hipMemsetAsync(deg, 0, (size_t)ND * 4, stream);
  hipMemsetAsync(bhist, 0, (size_t)NBUK * 4, stream);
  k_build_waug<<<(DINK * NAUG + 255) / 256, 256, 0, stream>>>(W, al, ar, Waug);
  k_hist_fused<<<1024, 256, 0, stream>>>(esrc, edst, deg, bhist);
  k_gemm_mfma<<<(NTOT + 63) / 64, 256, 0, stream>>>(fs, fd, Waug, hbf, el, er);
  k_scan_buckets<<<1, NBUK, 0, stream>>>(bhist, bcur);
  k_partition<<<NPB, 256, 0, stream>>>(esrc, edst, bcur, part);

  int nbD = (ND + 1023) / 1024;
  k_scan1<<<nbD, 1024, 0, stream>>>(deg, bsum, ND);
  k_scan2<<<1, 64, 0, stream>>>(bsum, nbD);
  k_scan3<<<nbD, 1024, 0, stream>>>(deg, bsum, offs, cur, ND);
  k_scatter_dst<<<(NE + 255) / 256, 256, 0, stream>>>(part, cur, csr);

  k_agg<<<ND / 4, 256, 0, stream>>>(csr, offs, deg, el, er, (const uint32_t*)hbf, bias, out);
}